// Round 3
// baseline (99.935 us; speedup 1.0000x reference)
//
#include <hip/hip_runtime.h>

// MQuantileLoss: B=4096 rows, N=8192 cols fp32.
// One wave per (row, matrix): lane owns 128 contiguous elements.
// Phase 1: strictly-sequential lane sum (same order as phase-2 walk).
// Wave shfl-scan -> exclusive lane bases. Owner lanes (<=3) re-walk their
// 512 B to find the reference's piecewise-linear quantile. 8 waves/block
// pair est/tgt rows via LDS; one atomicAdd per block.

constexpr int NCOL = 8192;
constexpr int LPT  = NCOL / 64;        // 128 elements per lane
constexpr int ROWS_PER_BLOCK = 4;      // waves 0-3: estimate, 4-7: target

__global__ __launch_bounds__(512, 8) void mquantile_wave(
    const float* __restrict__ pe, const float* __restrict__ pt,
    float* __restrict__ out, float inv_total)
{
    const int tid  = threadIdx.x;
    const int lane = tid & 63;
    const int wv   = tid >> 6;          // 0..7
    const int m    = wv >> 2;           // 0 = estimate, 1 = target
    const int rloc = wv & 3;
    const int row  = blockIdx.x * ROWS_PER_BLOCK + rloc;

    const float* rp = (m == 0 ? pe : pt) + (size_t)row * NCOL + (size_t)lane * LPT;

    // ---- phase 1: sequential lane sum, batched loads (4 float4 in flight) ----
    float run = 0.f;
    #pragma unroll
    for (int c = 0; c < LPT / 16; ++c) {          // 8 batches of 16 elements
        float4 v[4];
        #pragma unroll
        for (int k = 0; k < 4; ++k)
            v[k] = *reinterpret_cast<const float4*>(rp + c * 16 + k * 4);
        #pragma unroll
        for (int k = 0; k < 4; ++k) {
            run += v[k].x; run += v[k].y; run += v[k].z; run += v[k].w;
        }
    }
    const float lsum = run;

    // ---- wave inclusive scan of lane sums ----
    float x = lsum;
    #pragma unroll
    for (int off = 1; off < 64; off <<= 1) {
        const float y = __shfl_up(x, off, 64);
        if (lane >= off) x += y;
    }
    const float incl  = x;
    float excl = __shfl_up(x, 1, 64);
    if (lane == 0) excl = 0.f;
    const float total = __shfl(x, 63, 64);

    __shared__ float sc[8][3];

    // ---- phase 2: owner lanes walk their chunk ----
    const float qs[3] = {0.25f, 0.5f, 0.75f};
    #pragma unroll
    for (int qi = 0; qi < 3; ++qi) {
        const float q = qs[qi];
        // excl[] is monotone with excl[0]=0, incl==next lane's excl exactly
        // (same scan values), so exactly one lane matches; lane 63 catches
        // the (rounding-only) q > total clip case.
        const bool owner = (excl < q && incl >= q) || (lane == 63 && total < q);
        if (owner) {
            float runw = excl, prev = excl, Yb = 0.f, Ya = 0.f;
            int idx = -1;
            for (int c = 0; c < LPT / 4 && idx < 0; ++c) {
                const float4 v = *reinterpret_cast<const float4*>(rp + c * 4);
                const float vv[4] = {v.x, v.y, v.z, v.w};
                #pragma unroll
                for (int e = 0; e < 4; ++e) {
                    prev = runw; runw += vv[e];
                    if (idx < 0 && runw >= q) { idx = c * 4 + e; Yb = runw; Ya = prev; }
                }
            }
            if (idx < 0) { idx = LPT - 1; Yb = runw; Ya = prev; }   // clip fallback
            // score = (i+1) + (q - cdf[i]) / (cdf[i] - cdf[i-1]); Ya==0 at i==0
            // (lane 0's excl is exactly 0, matching the reference's (0,0) anchor).
            sc[wv][qi] = (float)(lane * LPT + idx + 1) + (q - Yb) / (Yb - Ya);
        }
    }
    __syncthreads();

    // ---- pair est/tgt scores, one atomic per block ----
    if (wv == 0) {
        float d = 0.f;
        if (lane < 12) {
            const int rl = lane / 3, qi = lane % 3;
            d = fabsf(sc[rl][qi] - sc[rl + 4][qi]);
        }
        #pragma unroll
        for (int off = 8; off > 0; off >>= 1) d += __shfl_down(d, off, 16);
        if (lane == 0) atomicAdd(out, d * inv_total);
    }
}

extern "C" void kernel_launch(void* const* d_in, const int* in_sizes, int n_in,
                              void* d_out, int out_size, void* d_ws, size_t ws_size,
                              hipStream_t stream) {
    const float* pe = (const float*)d_in[0];   // p_estimate
    const float* pt = (const float*)d_in[1];   // p_target
    const int B = in_sizes[0] / NCOL;
    hipMemsetAsync(d_out, 0, sizeof(float), stream);
    mquantile_wave<<<B / ROWS_PER_BLOCK, 512, 0, stream>>>(
        pe, pt, (float*)d_out, 1.0f / (3.0f * (float)B));
}

// Round 4
// 82.696 us; speedup vs baseline: 1.2085x; 1.2085x over previous
//
#include <hip/hip_runtime.h>

// MQuantileLoss: B=4096 rows, N=8192 cols fp32.
// Two-pass: (1) streaming coalesced chunk sums (128 el/chunk) -> d_ws;
// (2) per-(row,matrix) wave: scan 64 partials, owner lanes re-read their
// 512-B chunk and compute the reference's piecewise-linear quantile.

constexpr int NCOL  = 8192;
constexpr int CHUNK = 128;                 // elements per partial
constexpr int NCHNK = NCOL / CHUNK;        // 64 partials per row
constexpr int P1_GRID = 2048, P1_BLK = 256;

__global__ __launch_bounds__(P1_BLK) void chunk_sums(
    const float* __restrict__ pe, const float* __restrict__ pt,
    float* __restrict__ part, int f4_per_mat, int niter)
{
    const int gid    = blockIdx.x * P1_BLK + threadIdx.x;
    const int stride = P1_GRID * P1_BLK;
    // niter is even; 2 independent 1-KiB wave loads in flight per iteration.
    for (int i = 0; i < niter; i += 2) {
        const int f0 = gid + i * stride;
        const int f1 = gid + (i + 1) * stride;
        const float* s0 = (f0 < f4_per_mat) ? pe + (size_t)f0 * 4
                                            : pt + (size_t)(f0 - f4_per_mat) * 4;
        const float* s1 = (f1 < f4_per_mat) ? pe + (size_t)f1 * 4
                                            : pt + (size_t)(f1 - f4_per_mat) * 4;
        const float4 v0 = *reinterpret_cast<const float4*>(s0);
        const float4 v1 = *reinterpret_cast<const float4*>(s1);
        float a = v0.x + v0.y + v0.z + v0.w;
        float b = v1.x + v1.y + v1.z + v1.w;
        #pragma unroll
        for (int off = 1; off < 32; off <<= 1) {   // 32-lane group = one chunk
            a += __shfl_xor(a, off, 64);
            b += __shfl_xor(b, off, 64);
        }
        if ((threadIdx.x & 31) == 0) {
            part[f0 >> 5] = a;
            part[f1 >> 5] = b;
        }
    }
}

__global__ __launch_bounds__(512) void quantiles_from_parts(
    const float* __restrict__ pe, const float* __restrict__ pt,
    const float* __restrict__ part, float* __restrict__ out,
    int B, float inv_total)
{
    const int tid  = threadIdx.x;
    const int lane = tid & 63;
    const int wv   = tid >> 6;            // 0..7
    const int m    = wv >> 2;             // 0 = estimate, 1 = target
    const int row  = blockIdx.x * 4 + (wv & 3);
    const float* rp = (m == 0 ? pe : pt) + (size_t)row * NCOL;

    // lane's chunk partial; coalesced 256-B load
    const float p = part[((size_t)m * B + row) * NCHNK + lane];

    // wave inclusive scan
    float x = p;
    #pragma unroll
    for (int off = 1; off < 64; off <<= 1) {
        const float y = __shfl_up(x, off, 64);
        if (lane >= off) x += y;
    }
    const float incl  = x;
    float excl = __shfl_up(x, 1, 64);
    if (lane == 0) excl = 0.f;
    const float total = __shfl(x, 63, 64);

    __shared__ float sc[8][3];
    const float qs[3] = {0.25f, 0.5f, 0.75f};
    #pragma unroll
    for (int qi = 0; qi < 3; ++qi) {
        const float q = qs[qi];
        // incl_l == excl_{l+1} bitwise (same scan) -> exactly one owner;
        // lane 63 catches the rounding-only q > total clip case.
        const bool owner = (excl < q && incl >= q) || (lane == 63 && total < q);
        if (owner) {
            const float* cp = rp + (size_t)lane * CHUNK;
            float runw = excl, prev = excl, Yb = 0.f, Ya = 0.f;
            int idx = -1;
            for (int b0 = 0; b0 < CHUNK / 16 && idx < 0; ++b0) {
                float4 v[4];                       // 4 independent loads in flight
                #pragma unroll
                for (int k = 0; k < 4; ++k)
                    v[k] = *reinterpret_cast<const float4*>(cp + b0 * 16 + k * 4);
                #pragma unroll
                for (int k = 0; k < 4; ++k) {
                    const float vv[4] = {v[k].x, v[k].y, v[k].z, v[k].w};
                    #pragma unroll
                    for (int e = 0; e < 4; ++e) {
                        prev = runw; runw += vv[e];
                        if (idx < 0 && runw >= q) {
                            idx = b0 * 16 + k * 4 + e; Yb = runw; Ya = prev;
                        }
                    }
                }
            }
            if (idx < 0) { idx = CHUNK - 1; Yb = runw; Ya = prev; } // clip/rounding
            // score = (i+1) + (q - cdf[i]) / (cdf[i] - cdf[i-1]); Ya==0 at i==0
            // (lane 0's excl is exactly 0 -> reference's (0,0) anchor).
            sc[wv][qi] = (float)(lane * CHUNK + idx + 1) + (q - Yb) / (Yb - Ya);
        }
    }
    __syncthreads();

    if (wv == 0) {
        float d = 0.f;
        if (lane < 12) {
            const int rl = lane / 3, qi = lane % 3;
            d = fabsf(sc[rl][qi] - sc[rl + 4][qi]);
        }
        #pragma unroll
        for (int off = 8; off > 0; off >>= 1) d += __shfl_down(d, off, 16);
        if (lane == 0) atomicAdd(out, d * inv_total);
    }
}

extern "C" void kernel_launch(void* const* d_in, const int* in_sizes, int n_in,
                              void* d_out, int out_size, void* d_ws, size_t ws_size,
                              hipStream_t stream) {
    const float* pe = (const float*)d_in[0];   // p_estimate
    const float* pt = (const float*)d_in[1];   // p_target
    const int B = in_sizes[0] / NCOL;
    float* part = (float*)d_ws;                // [2*B*NCHNK] = 2 MB
    const int f4_per_mat = B * NCOL / 4;
    const int niter = (2 * f4_per_mat) / (P1_GRID * P1_BLK);   // 32 for B=4096

    hipMemsetAsync(d_out, 0, sizeof(float), stream);
    chunk_sums<<<P1_GRID, P1_BLK, 0, stream>>>(pe, pt, part, f4_per_mat, niter);
    quantiles_from_parts<<<B / 4, 512, 0, stream>>>(
        pe, pt, part, (float*)d_out, B, 1.0f / (3.0f * (float)B));
}